// Round 3
// baseline (452.761 us; speedup 1.0000x reference)
//
#include <hip/hip_runtime.h>
#include <stdint.h>

// out = x * mask, x: (16384, 4096) fp32.
// mask = jax.random.bernoulli(key(42), 0.9) * (1/0.9), cols < 64 forced to 0.
//
// JAX (threefry_partitionable=True, the modern default):
//   counter = (hi32(f), lo32(f)) of flat index f; key = (0, 42)
//   bits = threefry2x32(key, counter).word0 ^ .word1      (32-bit output path)
//   keep  <=>  (bits >> 9) < 7549747   <=>   bits < 0xE6666600u   (0.9f exact)
// For f < 2^26: hi32(f) == 0, so counter = (0, f).
//
// rotl via v_alignbit_b32: rotl(x,d) == alignbit(x, x, 32-d) — guarantees
// 3 VALU ops/round (add, alignbit, xor) instead of 5 if the compiler fails
// to pattern-match the shift-or idiom.

typedef float  vfloat4 __attribute__((ext_vector_type(4)));

#define ROTL(x, d) __builtin_amdgcn_alignbit((x), (x), 32u - (d))
#define TF_ROUND(x0, x1, d) { x0 += x1; x1 = ROTL(x1, d); x1 ^= x0; }

__device__ __forceinline__ uint32_t threefry_xor_key_0_42(uint32_t c1) {
    const uint32_t k1 = 42u;
    const uint32_t k2 = 0x1BD11BDAu ^ 42u;   // parity ^ k0 ^ k1, k0 = 0

    uint32_t x0 = 0u;            // c0 + k0 = 0
    uint32_t x1 = c1 + k1;

    TF_ROUND(x0, x1, 13) TF_ROUND(x0, x1, 15) TF_ROUND(x0, x1, 26) TF_ROUND(x0, x1, 6)
    x0 += k1; x1 += k2 + 1u;
    TF_ROUND(x0, x1, 17) TF_ROUND(x0, x1, 29) TF_ROUND(x0, x1, 16) TF_ROUND(x0, x1, 24)
    x0 += k2; x1 += 0u + 2u;     // k0 = 0
    TF_ROUND(x0, x1, 13) TF_ROUND(x0, x1, 15) TF_ROUND(x0, x1, 26) TF_ROUND(x0, x1, 6)
    x0 += 0u; x1 += k1 + 3u;
    TF_ROUND(x0, x1, 17) TF_ROUND(x0, x1, 29) TF_ROUND(x0, x1, 16) TF_ROUND(x0, x1, 24)
    x0 += k1; x1 += k2 + 4u;
    TF_ROUND(x0, x1, 13) TF_ROUND(x0, x1, 15) TF_ROUND(x0, x1, 26) TF_ROUND(x0, x1, 6)
    x0 += k2; x1 += 0u + 5u;

    return x0 ^ x1;              // partitionable 32-bit output: word0 ^ word1
}

__global__ __launch_bounds__(256) void mydropout_attack_kernel(
        const float* __restrict__ x, float* __restrict__ out, unsigned int n) {
    // Each thread: 8 consecutive elements [base, base+8). n % (8*256) == 0.
    unsigned int base = (blockIdx.x * 256u + threadIdx.x) * 8u;
    if (base >= n) return;

    const float    SCALE    = (float)(1.0 / 0.9);  // jnp.asarray(1.0/0.9, f32)
    const uint32_t THRESH_B = 0xE6666600u;         // 7549747u << 9 (exact compare on raw bits)
    const unsigned int NCOLS = 4096u;
    const unsigned int KCOLS = 64u;

    vfloat4 a = *reinterpret_cast<const vfloat4*>(x + base);
    vfloat4 b = *reinterpret_cast<const vfloat4*>(x + base + 4);

    float m[8];
#pragma unroll
    for (int k = 0; k < 8; ++k) {
        uint32_t bits = threefry_xor_key_0_42(base + (uint32_t)k);
        m[k] = (bits < THRESH_B) ? SCALE : 0.0f;
    }

    // Column kill: base % 8 == 0 and 64 % 8 == 0, so all 8 elements share the
    // (col < 64) predicate.
    if ((base & (NCOLS - 1u)) < KCOLS) {
#pragma unroll
        for (int k = 0; k < 8; ++k) m[k] = 0.0f;
    }

    vfloat4 oa, ob;
    oa.x = a.x * m[0]; oa.y = a.y * m[1]; oa.z = a.z * m[2]; oa.w = a.w * m[3];
    ob.x = b.x * m[4]; ob.y = b.y * m[5]; ob.z = b.z * m[6]; ob.w = b.w * m[7];

    // Output is write-once, never re-read: non-temporal store bypasses L2 fill.
    __builtin_nontemporal_store(oa, reinterpret_cast<vfloat4*>(out + base));
    __builtin_nontemporal_store(ob, reinterpret_cast<vfloat4*>(out + base + 4));
}

extern "C" void kernel_launch(void* const* d_in, const int* in_sizes, int n_in,
                              void* d_out, int out_size, void* d_ws, size_t ws_size,
                              hipStream_t stream) {
    const float* x = (const float*)d_in[0];
    float* out = (float*)d_out;

    unsigned int n = (unsigned int)out_size;        // 16384*4096 = 2^26
    unsigned int work = n / 8u;                     // one thread per 8 elements
    unsigned int threads = 256u;
    unsigned int blocks = (work + threads - 1u) / threads;

    mydropout_attack_kernel<<<dim3(blocks), dim3(threads), 0, stream>>>(x, out, n);
}